// Round 11
// baseline (67.925 us; speedup 1.0000x reference)
//
#include <hip/hip_runtime.h>

#define B_ 4
#define C_ 128
#define H_ 128
#define W_ 256
#define HW_ (H_ * W_)
#define ND 81
#define TH 8          // output rows per block
#define TW 16         // output cols per block
#define HR 16         // f2 halo rows  (TH + 8)
#define WCOL 32       // f2 halo cols
#define KC 32         // channels per LDS chunk (= MFMA K)
#define NCHUNK (C_ / KC)
#define NTHREADS 512
#define BUFSZ 40960   // 32 KB f2 (512 px * 64B) + 8 KB f1 (128 px * 64B)
#define F1OFF 32768

typedef short bf16x8 __attribute__((ext_vector_type(8)));
typedef float f32x4 __attribute__((ext_vector_type(4)));
typedef unsigned int u32x4 __attribute__((ext_vector_type(4)));

// Pixel-major LDS: px block = 64 B (32 ch bf16), 4 slots of 16 B.
// Slot permutation slot' = slot ^ (px&3) ^ ((px>>2)&3) — derived to give an
// even 8-lanes-per-bank-group distribution for BOTH ds_write_b128 staging
// (lanes vary px) and ds_read_b128 MFMA fragments (lanes vary col,quad).
// Bijective per px block. Row/tile steps (+32 px, +16 px) preserve the
// XOR term, so MFMA reads use ONE vaddr + imm offsets (dy*2048, +1024).
__device__ __forceinline__ int slotswz(int px, int slot) {
    return px * 64 + ((slot ^ (px & 3) ^ ((px >> 2) & 3)) * 16);
}

// Native packed fp32->bf16 (gfx950); A/B share the packing so dots invariant.
__device__ __forceinline__ unsigned int cvt_pk_bf16(float a, float b) {
    unsigned int r;
    asm("v_cvt_pk_bf16_f32 %0, %1, %2" : "=v"(r) : "v"(a), "v"(b));
    return r;
}

// ss += lo(u)^2 + hi(u)^2 in one VOP3P instruction (R10-verified).
__device__ __forceinline__ void dot2_sq(unsigned int u, float& ss) {
    asm("v_dot2_f32_bf16 %0, %1, %1, %0" : "+v"(ss) : "v"(u));
}

// Barrier WITHOUT vmcnt drain (R6-verified): LDS ordered, globals stay in flight.
#define BARRIER()                                             \
    do {                                                      \
        asm volatile("s_waitcnt lgkmcnt(0)" ::: "memory");    \
        __builtin_amdgcn_s_barrier();                         \
    } while (0)

__global__ __launch_bounds__(NTHREADS)
void corr81_kernel(const float* __restrict__ f1g, const float* __restrict__ f2g,
                   float* __restrict__ out) {
    __shared__ __align__(16) char lds[2][BUFSZ];   // 80 KB -> 2 blocks/CU
    char* ldsc = &lds[0][0];
    // invn overlays buf0 (free after k=2's barrier; written at k=3; read post-barrier)
    float* invn2 = (float*)&lds[0][0];      // 512 floats
    float* invn1 = (float*)&lds[0][2048];   // 128 floats

    const int tid  = threadIdx.x;
    const int lane = tid & 63;
    const int wave = tid >> 6;
    const int col  = lane & 15;
    const int quad = lane >> 4;

    // XCD-aware block swizzle (T1, verified R4). Bijective: 1024 = 8*128.
    const int flat = blockIdx.x + 16 * blockIdx.y + 256 * blockIdx.z;
    const int orig = (flat & 7) * 128 + (flat >> 3);
    const int w0 = (orig & 15) * TW;
    const int h0 = ((orig >> 4) & 15) * TH;
    const int b  = orig >> 8;
    const float* f2base = f2g + (size_t)b * C_ * HW_;
    const float* f1base = f1g + (size_t)b * C_ * HW_;

    // ---- f2 staging: thread owns pixel tid of the 16x32 halo ----
    const int hh2 = tid >> 5, ww2 = tid & 31;
    const int gh2 = h0 - 4 + hh2, gw2 = w0 - 4 + ww2;
    const bool v2 = (gh2 >= 0) && (gh2 < H_) && (gw2 >= 0) && (gw2 < W_);
    const int offs2 = v2 ? (gh2 * W_ + gw2) : 0;
    int wa[4];
#pragma unroll
    for (int s = 0; s < 4; ++s) wa[s] = slotswz(tid, s);

    // ---- f1 staging: 4 threads per pixel, 8 channels each ----
    const int px1w = tid >> 2, q1 = tid & 3;
    const int offs1 = (h0 + (px1w >> 4)) * W_ + (w0 + (px1w & 15)) + q1 * 8 * HW_;
    const int w1a = F1OFF + slotswz(px1w, q1);

    // ---- MFMA read addresses: ONE vaddr each, imm offsets for dy/tile/buf ----
    const int slotr = (quad ^ (col & 3) ^ ((col >> 2) & 3)) * 16;
    const int rb2 = wave * 2048 + col * 64 + slotr;
    const int rb1 = F1OFF + (wave * 16 + col) * 64 + slotr;

    f32x4 acc[9][2];
#pragma unroll
    for (int d = 0; d < 9; ++d) { acc[d][0] = (f32x4)0.f; acc[d][1] = (f32x4)0.f; }

    // prefetch regs: zero-init once; invalid lanes stay 0 (loads exec-masked)
    f32x4 A[8] = {};
    f32x4 F[2] = {};
    float ss2a = 0.f, ss2b = 0.f, ss1 = 0.f;

#define ISSUE_F2(kc0)                                                           \
    if (v2) {                                                                   \
        _Pragma("unroll")                                                       \
        for (int c = 0; c < 32; ++c)                                            \
            A[c >> 2][c & 3] = (f2base + (size_t)((kc0) + c) * HW_)[offs2];     \
    }

#define ISSUE_F1(kc0)                                                           \
    {                                                                           \
        _Pragma("unroll")                                                       \
        for (int j = 0; j < 8; ++j)                                             \
            F[j >> 2][j & 3] = (f1base + (size_t)((kc0) + j) * HW_)[offs1];     \
    }

#define PACK_F2(buf)                                                            \
    {                                                                           \
        _Pragma("unroll")                                                       \
        for (int s = 0; s < 4; ++s) {                                           \
            u32x4 U;                                                            \
            U[0] = cvt_pk_bf16(A[s * 2][0], A[s * 2][1]);                       \
            U[1] = cvt_pk_bf16(A[s * 2][2], A[s * 2][3]);                       \
            U[2] = cvt_pk_bf16(A[s * 2 + 1][0], A[s * 2 + 1][1]);               \
            U[3] = cvt_pk_bf16(A[s * 2 + 1][2], A[s * 2 + 1][3]);               \
            dot2_sq(U[0], ss2a); dot2_sq(U[1], ss2b);                           \
            dot2_sq(U[2], ss2a); dot2_sq(U[3], ss2b);                           \
            *(u32x4*)(ldsc + (buf) * BUFSZ + wa[s]) = U;                        \
        }                                                                       \
    }

#define PACK_F1(buf)                                                            \
    {                                                                           \
        u32x4 U;                                                                \
        U[0] = cvt_pk_bf16(F[0][0], F[0][1]);                                   \
        U[1] = cvt_pk_bf16(F[0][2], F[0][3]);                                   \
        U[2] = cvt_pk_bf16(F[1][0], F[1][1]);                                   \
        U[3] = cvt_pk_bf16(F[1][2], F[1][3]);                                   \
        dot2_sq(U[0], ss1); dot2_sq(U[1], ss1);                                 \
        dot2_sq(U[2], ss1); dot2_sq(U[3], ss1);                                 \
        *(u32x4*)(ldsc + (buf) * BUFSZ + w1a) = U;                              \
    }

#define MFMA_PHASE(buf)                                                         \
    {                                                                           \
        const char* rb = ldsc + (buf) * BUFSZ;                                  \
        bf16x8 af = *(const bf16x8*)(rb + rb1);                                 \
        _Pragma("unroll")                                                       \
        for (int dy = 0; dy < 9; ++dy) {                                        \
            bf16x8 b0 = *(const bf16x8*)(rb + rb2 + dy * 2048);                 \
            bf16x8 b1 = *(const bf16x8*)(rb + rb2 + dy * 2048 + 1024);          \
            acc[dy][0] = __builtin_amdgcn_mfma_f32_16x16x32_bf16(af, b0, acc[dy][0], 0, 0, 0); \
            acc[dy][1] = __builtin_amdgcn_mfma_f32_16x16x32_bf16(af, b1, acc[dy][1], 0, 0, 0); \
        }                                                                       \
    }

    // ---- prologue ----
    ISSUE_F2(0); ISSUE_F1(0);
    PACK_F2(0);  PACK_F1(0);
    ISSUE_F2(KC); ISSUE_F1(KC);
    BARRIER();

    // ---- main: one barrier per chunk; norms folded into pack ----
#pragma unroll
    for (int k = 0; k < NCHUNK; ++k) {
        const int bk = k & 1;
        MFMA_PHASE(bk);
        if (k < NCHUNK - 1) {
            PACK_F2(bk ^ 1); PACK_F1(bk ^ 1);
            if (k < NCHUNK - 2) { ISSUE_F2((k + 2) * KC); ISSUE_F1((k + 2) * KC); }
            BARRIER();
        }
    }

    // ---- norms (all channels accumulated during packs) ----
    invn2[tid] = 1.f / fmaxf(sqrtf(ss2a + ss2b), 1e-12f);
    float t1 = ss1 + __shfl_xor(ss1, 1);
    t1 += __shfl_xor(t1, 2);
    if (q1 == 0) invn1[px1w] = 1.f / fmaxf(sqrtf(t1), 1e-12f);
    BARRIER();

    // ---- epilogue: extract band, rescale, leaky-relu, store ----
    const int hOut = h0 + wave;
    float* outB = out + (size_t)b * ND * HW_ + (size_t)hOut * W_;
    const float scale = 1.f / (float)C_;

#pragma unroll
    for (int dy = 0; dy < 9; ++dy) {
        int hr = wave + dy;
#pragma unroll
        for (int t = 0; t < 2; ++t) {
            float i2 = invn2[hr * WCOL + t * 16 + col];
#pragma unroll
            for (int r = 0; r < 4; ++r) {
                int row = quad * 4 + r;
                int dx = t * 16 + col - row;
                if (dx >= 0 && dx <= 8) {
                    float v = acc[dy][t][r] * invn1[wave * 16 + row] * i2 * scale;
                    v = (v >= 0.f) ? v : 0.1f * v;
                    outB[(size_t)(dy * 9 + dx) * HW_ + (w0 + row)] = v;
                }
            }
        }
    }
#undef ISSUE_F2
#undef ISSUE_F1
#undef PACK_F2
#undef PACK_F1
#undef MFMA_PHASE
}

extern "C" void kernel_launch(void* const* d_in, const int* in_sizes, int n_in,
                              void* d_out, int out_size, void* d_ws, size_t ws_size,
                              hipStream_t stream) {
    const float* f1 = (const float*)d_in[0];
    const float* f2 = (const float*)d_in[1];
    float* out = (float*)d_out;
    dim3 grid(W_ / TW, H_ / TH, B_);   // 16 x 16 x 4 = 1024 blocks
    corr81_kernel<<<grid, NTHREADS, 0, stream>>>(f1, f2, out);
}

// Round 12
// 67.333 us; speedup vs baseline: 1.0088x; 1.0088x over previous
//
#include <hip/hip_runtime.h>

#define B_ 4
#define C_ 128
#define H_ 128
#define W_ 256
#define HW_ (H_ * W_)
#define ND 81
#define TH 8          // output rows per block
#define TW 16         // output cols per block
#define HR 16         // f2 halo rows  (TH + 8)
#define WCOL 32       // f2 halo cols
#define KC 32         // channels per LDS chunk (= MFMA K)
#define NCHUNK (C_ / KC)
#define NTHREADS 512

typedef short bf16x8 __attribute__((ext_vector_type(8)));
typedef float f32x4 __attribute__((ext_vector_type(4)));
typedef float f32x4v __attribute__((ext_vector_type(4)));
typedef unsigned int u32x4 __attribute__((ext_vector_type(4)));

// Swizzle (HW-verified R1/R3-R10): XOR bits 4..6 of the full byte address by
// (r & 7) << 4 where r = px>>1 lives in bits >=7. Bijective.
__device__ __forceinline__ int swz(int px, int byteInHalf) {
    int r = px >> 1;
    int base = (r << 7) + ((px & 1) << 6) + byteInHalf;
    return base ^ ((r & 7) << 4);
}

// Native packed fp32->bf16 convert (gfx950). A/B use the same packing so the
// MFMA dot is invariant to lo/hi order.
__device__ __forceinline__ unsigned int cvt_pk_bf16(float a, float b) {
    unsigned int r;
    asm("v_cvt_pk_bf16_f32 %0, %1, %2" : "=v"(r) : "v"(a), "v"(b));
    return r;
}

// ss += lo(u)^2 + hi(u)^2 in one VOP3P instruction (R10-verified).
__device__ __forceinline__ void dot2_sq(unsigned int u, float& ss) {
    asm("v_dot2_f32_bf16 %0, %1, %1, %0" : "+v"(ss) : "v"(u));
}

// Barrier WITHOUT vmcnt drain (R6-verified): LDS ordered, globals in flight.
#define BARRIER()                                             \
    do {                                                      \
        asm volatile("s_waitcnt lgkmcnt(0)" ::: "memory");    \
        __builtin_amdgcn_s_barrier();                         \
    } while (0)

__global__ __launch_bounds__(NTHREADS)
void corr81_kernel(const float* __restrict__ f1g, const float* __restrict__ f2g,
                   float* __restrict__ out) {
    // Double-buffered staging: exactly 80 KB -> 2 blocks/CU.
    __shared__ __align__(16) unsigned short f2s[2][HR * WCOL * KC];  // 2 x 32 KB
    __shared__ __align__(16) unsigned short f1s[2][TH * TW * KC];    // 2 x 8 KB
    // invn arrays overlay buf0 (hazard-free; epilogue reads post-barrier).
    float* invn2 = (float*)&f2s[0][0];   // 512 floats @ bytes 0..2048
    float* invn1 = (float*)&f1s[0][0];   // 128 floats
    // Transposed-output slab: 8 waves x 81ch x 16w floats = 41472 B at byte
    // 2048 of the f2s region (2048..43520) — free after the final MFMA.
    float* tbase = (float*)((char*)&f2s[0][0] + 2048);

    const int tid  = threadIdx.x;
    const int lane = tid & 63;
    const int wave = tid >> 6;            // 0..7 -> output row within tile
    const int col  = lane & 15;
    const int quad = lane >> 4;

    // XCD-aware block swizzle (T1, verified R4). Bijective: 1024 = 8*128.
    const int flat = blockIdx.x + 16 * blockIdx.y + 256 * blockIdx.z;
    const int orig = (flat & 7) * 128 + (flat >> 3);
    const int w0 = (orig & 15) * TW;
    const int h0 = ((orig >> 4) & 15) * TH;
    const int b  = orig >> 8;
    const size_t inBase = (size_t)b * C_ * HW_;

    // f2 staging: (i 0..3) x per-thread (g2, cp2, rq)
    const int g2  = tid & 7;
    const int cp2 = (tid >> 3) & 15;
    const int rq  = tid >> 7;
    const int gw2 = w0 - 4 + g2 * 4;
    const bool colok2 = (gw2 >= 0) && (gw2 < W_);

    // f1 staging: one float4-pair per thread
    const int g1  = tid & 3;
    const int cp1 = (tid >> 2) & 15;
    const int r1  = tid >> 6;
    const float* src1 = f1g + inBase + (size_t)(h0 + r1) * W_ + (w0 + g1 * 4);

    const int aOff = swz(wave * 16 + col, quad * 16);

    f32x4 acc[9][2];
#pragma unroll
    for (int d = 0; d < 9; ++d) {
        acc[d][0] = (f32x4)0.f;
        acc[d][1] = (f32x4)0.f;
    }

    float ss2 = 0.f, ss1 = 0.f;
    f32x4v A0[4], A1[4], B0, B1;

#define ISSUE_LOADS(kc0)                                                        \
    {                                                                           \
        _Pragma("unroll")                                                       \
        for (int i = 0; i < 4; ++i) {                                           \
            int r  = i * 4 + rq;                                                \
            int gh = h0 - 4 + r;                                                \
            if (colok2 && gh >= 0 && gh < H_) {                                 \
                const float* s = f2g + inBase + (size_t)((kc0) + cp2 * 2) * HW_ \
                                 + (size_t)gh * W_ + gw2;                       \
                A0[i] = *(const f32x4v*)s;                                      \
                A1[i] = *(const f32x4v*)(s + HW_);                              \
            } else {                                                            \
                A0[i] = (f32x4v)0.f;                                            \
                A1[i] = (f32x4v)0.f;                                            \
            }                                                                   \
        }                                                                       \
        const float* s = src1 + (size_t)((kc0) + cp1 * 2) * HW_;                \
        B0 = *(const f32x4v*)s;                                                 \
        B1 = *(const f32x4v*)(s + HW_);                                         \
    }

#define PACK_WRITE(buf)                                                         \
    {                                                                           \
        char* w2 = (char*)&f2s[(buf)][0];                                       \
        char* w1 = (char*)&f1s[(buf)][0];                                       \
        _Pragma("unroll")                                                       \
        for (int i = 0; i < 4; ++i) {                                           \
            int r = i * 4 + rq;                                                 \
            _Pragma("unroll")                                                   \
            for (int j = 0; j < 4; ++j) {                                       \
                int px = r * 32 + g2 * 4 + j;                                   \
                *(unsigned int*)(w2 + swz(px, cp2 * 4)) =                       \
                    cvt_pk_bf16(A0[i][j], A1[i][j]);                            \
            }                                                                   \
        }                                                                       \
        _Pragma("unroll")                                                       \
        for (int j = 0; j < 4; ++j) {                                           \
            int px = r1 * 16 + g1 * 4 + j;                                      \
            *(unsigned int*)(w1 + swz(px, cp1 * 4)) = cvt_pk_bf16(B0[j], B1[j]);\
        }                                                                       \
    }

#define MFMA_PHASE(buf)                                                         \
    {                                                                           \
        const char* r2 = (const char*)&f2s[(buf)][0];                           \
        const char* r1p = (const char*)&f1s[(buf)][0];                          \
        bf16x8 af = *(const bf16x8*)(r1p + aOff);                               \
        _Pragma("unroll")                                                       \
        for (int dy = 0; dy < 9; ++dy) {                                        \
            int pb = (wave + dy) * WCOL + col;                                  \
            bf16x8 b0 = *(const bf16x8*)(r2 + swz(pb, quad * 16));              \
            bf16x8 b1 = *(const bf16x8*)(r2 + swz(pb + 16, quad * 16));         \
            acc[dy][0] = __builtin_amdgcn_mfma_f32_16x16x32_bf16(af, b0, acc[dy][0], 0, 0, 0); \
            acc[dy][1] = __builtin_amdgcn_mfma_f32_16x16x32_bf16(af, b1, acc[dy][1], 0, 0, 0); \
        }                                                                       \
    }

#define NORM_PHASE(buf)                                                         \
    {                                                                           \
        const char* r2 = (const char*)&f2s[(buf)][0];                           \
        const char* r1p = (const char*)&f1s[(buf)][0];                          \
        _Pragma("unroll")                                                       \
        for (int j = 0; j < 4; ++j) {                                           \
            u32x4 v = *(const u32x4*)(r2 + swz(tid, j * 16));                   \
            dot2_sq(v[0], ss2); dot2_sq(v[1], ss2);                             \
            dot2_sq(v[2], ss2); dot2_sq(v[3], ss2);                             \
        }                                                                       \
        u32x4 v = *(const u32x4*)(r1p + swz(tid >> 2, (tid & 3) * 16));         \
        dot2_sq(v[0], ss1); dot2_sq(v[1], ss1);                                 \
        dot2_sq(v[2], ss1); dot2_sq(v[3], ss1);                                 \
    }

    // ---- prologue: stage chunk 0 into buf0, issue chunk-1 loads ----
    ISSUE_LOADS(0);
    PACK_WRITE(0);
    ISSUE_LOADS(KC);
    BARRIER();

    // ---- main: one barrier per chunk (R10-verified structure) ----
#pragma unroll
    for (int k = 0; k < NCHUNK; ++k) {
        const int bk = k & 1;
        MFMA_PHASE(bk);
        if (k < NCHUNK - 1) {
            PACK_WRITE(bk ^ 1);
            if (k < NCHUNK - 2) ISSUE_LOADS((k + 2) * KC);
            NORM_PHASE(bk);
        } else {
            NORM_PHASE(bk);
            invn2[tid] = 1.f / fmaxf(sqrtf(ss2), 1e-12f);
            float t1 = ss1 + __shfl_xor(ss1, 1);
            t1 += __shfl_xor(t1, 2);
            if ((tid & 3) == 0) invn1[tid >> 2] = 1.f / fmaxf(sqrtf(t1), 1e-12f);
        }
        BARRIER();
    }

    // ---- epilogue v2: scatter (scaled+activated) band into per-wave LDS
    // slab [ch][16w], then store COALESCED float4s (16 beats/instr vs ~1
    // beat/lane scattered dword stores — the R12 change) ----
    const float scale = 1.f / (float)C_;
    float* tw = tbase + wave * (ND * 16);

#pragma unroll
    for (int dy = 0; dy < 9; ++dy) {
        int hr = wave + dy;
#pragma unroll
        for (int t = 0; t < 2; ++t) {
            float i2 = invn2[hr * WCOL + t * 16 + col];
#pragma unroll
            for (int r = 0; r < 4; ++r) {
                int row = quad * 4 + r;
                int dx = t * 16 + col - row;
                if (dx >= 0 && dx <= 8) {
                    float v = acc[dy][t][r] * invn1[wave * 16 + row] * i2 * scale;
                    v = (v >= 0.f) ? v : 0.1f * v;
                    tw[(dy * 9 + dx) * 16 + row] = v;
                }
            }
        }
    }
    BARRIER();

    const int hOut = h0 + wave;
    float* outW = out + (size_t)b * ND * HW_ + (size_t)hOut * W_ + w0 + (lane & 3) * 4;
#pragma unroll
    for (int p = 0; p < 6; ++p) {
        int ch = p * 16 + (lane >> 2);
        if (ch < ND) {
            f32x4 vv = *(const f32x4*)(tw + ch * 16 + (lane & 3) * 4);
            *(f32x4*)(outW + (size_t)ch * HW_) = vv;
        }
    }
#undef ISSUE_LOADS
#undef PACK_WRITE
#undef MFMA_PHASE
#undef NORM_PHASE
}

extern "C" void kernel_launch(void* const* d_in, const int* in_sizes, int n_in,
                              void* d_out, int out_size, void* d_ws, size_t ws_size,
                              hipStream_t stream) {
    const float* f1 = (const float*)d_in[0];
    const float* f2 = (const float*)d_in[1];
    float* out = (float*)d_out;
    dim3 grid(W_ / TW, H_ / TH, B_);   // 16 x 16 x 4 = 1024 blocks
    corr81_kernel<<<grid, NTHREADS, 0, stream>>>(f1, f2, out);
}